// Round 1
// baseline (1141.811 us; speedup 1.0000x reference)
//
#include <hip/hip_runtime.h>

// BlkQ4Linear: out[m,n] = sum_k in[m,k] * (q[n,k]-zp[n,k/64])*s[n,k/64] + bias[n]
// M=4096 K=4096 N=11008. Strategy: fused dequant -> bf16 MFMA GEMM.
// 128x128 tile, BK=64 (== quant block, so one (s,zp) per staged B row per tile).

#define BM 128
#define BN 128
#define BK 64
#define LDSN 72  // padded LDS row (bf16 elems): 64+8 keeps b128 frag reads <=2-way banked

typedef __attribute__((ext_vector_type(8))) short bf16x8;
typedef __attribute__((ext_vector_type(4))) float f32x4;

__device__ __forceinline__ unsigned short f2bf(float f) {
    union { float f; unsigned int u; } v; v.f = f;
    unsigned int u = v.u;
    u += 0x7FFFu + ((u >> 16) & 1u);   // round-to-nearest-even
    return (unsigned short)(u >> 16);
}

__device__ __forceinline__ unsigned int pack2(float a, float b) {
    return (unsigned int)f2bf(a) | ((unsigned int)f2bf(b) << 16);
}

__global__ __launch_bounds__(256, 2)
void q4gemm_kernel(const float* __restrict__ A, const int* __restrict__ Q,
                   const float* __restrict__ S, const int* __restrict__ Zp,
                   const float* __restrict__ bias, float* __restrict__ C,
                   int M, int N, int K, int nb)
{
    __shared__ __align__(16) unsigned short As[BM * LDSN];
    __shared__ __align__(16) unsigned short Bs[BN * LDSN];

    const int tid = threadIdx.x;
    const int m0  = blockIdx.x * BM;   // M-tile fastest-varying: consecutive blocks
    const int n0  = blockIdx.y * BN;   // share the same 2MB B panel (L2-resident)

    // staging indices: 256 threads, 16 threads x 16 rows per iter, float4/int4 per thread
    const int srow = tid >> 4;          // 0..15
    const int scol = (tid & 15) << 2;   // element col, x4

    // wave/fragment indices
    const int lane = tid & 63;
    const int wave = tid >> 6;          // 4 waves, 2x2 -> 64x64 each
    const int wm   = (wave >> 1) * 64;
    const int wn   = (wave & 1) * 64;
    const int fr   = lane & 15;         // fragment row (m for A, n for B), also D col
    const int quad = lane >> 4;         // k-octet select; also D row group

    f32x4 acc[4][4];
    #pragma unroll
    for (int i = 0; i < 4; ++i)
        #pragma unroll
        for (int j = 0; j < 4; ++j)
            acc[i][j] = (f32x4){0.f, 0.f, 0.f, 0.f};

    const int ktiles = K / BK;
    for (int kt = 0; kt < ktiles; ++kt) {
        const int k0 = kt * BK;

        // --- stage A: fp32 -> bf16 ---
        #pragma unroll
        for (int i = 0; i < 8; ++i) {
            const int r = i * 16 + srow;
            const float4 v = *(const float4*)(A + (size_t)(m0 + r) * K + k0 + scol);
            uint2 p; p.x = pack2(v.x, v.y); p.y = pack2(v.z, v.w);
            *(uint2*)&As[r * LDSN + scol] = p;
        }
        // --- stage B: int code -> (q - zp)*s -> bf16 ---
        #pragma unroll
        for (int i = 0; i < 8; ++i) {
            const int r = i * 16 + srow;
            const int n = n0 + r;
            const int4 q = *(const int4*)(Q + (size_t)n * K + k0 + scol);
            const float s  = S[(size_t)n * nb + kt];
            const float zs = (float)Zp[(size_t)n * nb + kt] * s;
            uint2 p;
            p.x = pack2((float)q.x * s - zs, (float)q.y * s - zs);
            p.y = pack2((float)q.z * s - zs, (float)q.w * s - zs);
            *(uint2*)&Bs[r * LDSN + scol] = p;
        }
        __syncthreads();

        // --- compute: 2 k-steps of 16x16x32 MFMA, 4x4 fragments per wave ---
        #pragma unroll
        for (int ks = 0; ks < 2; ++ks) {
            bf16x8 af[4], bfg[4];
            #pragma unroll
            for (int i = 0; i < 4; ++i)
                af[i] = *(const bf16x8*)&As[(wm + i * 16 + fr) * LDSN + ks * 32 + quad * 8];
            #pragma unroll
            for (int j = 0; j < 4; ++j)
                bfg[j] = *(const bf16x8*)&Bs[(wn + j * 16 + fr) * LDSN + ks * 32 + quad * 8];
            #pragma unroll
            for (int i = 0; i < 4; ++i)
                #pragma unroll
                for (int j = 0; j < 4; ++j)
                    acc[i][j] = __builtin_amdgcn_mfma_f32_16x16x32_bf16(af[i], bfg[j], acc[i][j], 0, 0, 0);
        }
        __syncthreads();
    }

    // --- epilogue: D layout col = lane&15 (n), row = quad*4 + reg (m) ---
    #pragma unroll
    for (int j = 0; j < 4; ++j) {
        const int n = n0 + wn + j * 16 + fr;
        const float bv = bias[n];
        #pragma unroll
        for (int i = 0; i < 4; ++i) {
            const int mb = m0 + wm + i * 16 + quad * 4;
            #pragma unroll
            for (int r = 0; r < 4; ++r)
                C[(size_t)(mb + r) * N + n] = acc[i][j][r] + bv;
        }
    }
}

extern "C" void kernel_launch(void* const* d_in, const int* in_sizes, int n_in,
                              void* d_out, int out_size, void* d_ws, size_t ws_size,
                              hipStream_t stream) {
    const float* A    = (const float*)d_in[0];  // [M,K] fp32
    const int*   Q    = (const int*)d_in[1];    // [N,K] int codes 0..15
    const float* S    = (const float*)d_in[2];  // [N,nb]
    const int*   Zp   = (const int*)d_in[3];    // [N,nb]
    const float* bias = (const float*)d_in[4];  // [N]
    float* C = (float*)d_out;                   // [M,N] fp32

    const int N  = in_sizes[4];
    const int K  = in_sizes[1] / N;
    const int M  = in_sizes[0] / K;
    const int nb = in_sizes[2] / N;

    dim3 grid(M / BM, N / BN);
    q4gemm_kernel<<<grid, dim3(256), 0, stream>>>(A, Q, S, Zp, bias, C, M, N, K, nb);
}

// Round 2
// 778.125 us; speedup vs baseline: 1.4674x; 1.4674x over previous
//
#include <hip/hip_runtime.h>

// BlkQ4Linear: out[m,n] = sum_k in[m,k]*(q[n,k]-zp[n,k/64])*s[n,k/64] + bias[n]
// M=4096 K=4096 N=11008.
// Round 2: two-pass. Pass 1: dequant Q -> bf16 W and convert A -> bf16 in d_ws
// (removes 32x-redundant per-tile dequant VALU work). Pass 2: m97-structure
// bf16 MFMA GEMM with global_load_lds width-16 async staging (no VGPR round-trip).
// Falls back to round-1 fused kernel if ws_size < 124 MB.

#define BM 128
#define BN 128
#define BK 64
#define LDSN 72  // fused-fallback LDS pad

typedef __attribute__((ext_vector_type(8))) short bf16x8;
typedef __attribute__((ext_vector_type(4))) float f32x4;

__device__ __forceinline__ unsigned short f2bf(float f) {
    union { float f; unsigned int u; } v; v.f = f;
    unsigned int u = v.u;
    u += 0x7FFFu + ((u >> 16) & 1u);   // RNE
    return (unsigned short)(u >> 16);
}
__device__ __forceinline__ unsigned int pack2(float a, float b) {
    return (unsigned int)f2bf(a) | ((unsigned int)f2bf(b) << 16);
}

__device__ __forceinline__ void gl_lds16(const void* gp, void* lp) {
    __builtin_amdgcn_global_load_lds(
        (const __attribute__((address_space(1))) unsigned int*)gp,
        (__attribute__((address_space(3))) unsigned int*)lp,
        16, 0, 0);
}

// ---------------- Pass 1a: A fp32 -> bf16 ----------------
__global__ __launch_bounds__(256)
void a2bf_kernel(const float* __restrict__ A, unsigned short* __restrict__ Ab,
                 long total4)
{
    long t = (long)blockIdx.x * blockDim.x + threadIdx.x;
    if (t >= total4) return;
    float4 v = ((const float4*)A)[t];
    uint2 p; p.x = pack2(v.x, v.y); p.y = pack2(v.z, v.w);
    ((uint2*)Ab)[t] = p;
}

// ---------------- Pass 1b: Q int32 codes -> bf16 W ----------------
__global__ __launch_bounds__(256)
void dequant_kernel(const int* __restrict__ Q, const float* __restrict__ S,
                    const int* __restrict__ Zp, unsigned short* __restrict__ W,
                    int N, int K, int nb)
{
    // 8 codes per thread (32B read, 16B write); 8 | 64 so one (s,zp) per thread
    long t = (long)blockIdx.x * blockDim.x + threadIdx.x;
    long total = (long)N * K / 8;
    if (t >= total) return;
    int per_row = K >> 3;
    int n = (int)(t / per_row);
    int r = (int)(t % per_row);
    int k = r << 3;
    int kb = k >> 6;
    float s  = S[(size_t)n * nb + kb];
    float zs = (float)Zp[(size_t)n * nb + kb] * s;
    const int4* qp = (const int4*)(Q + (size_t)n * K + k);
    int4 q0 = qp[0], q1 = qp[1];
    uint4 o;
    o.x = pack2((float)q0.x * s - zs, (float)q0.y * s - zs);
    o.y = pack2((float)q0.z * s - zs, (float)q0.w * s - zs);
    o.z = pack2((float)q1.x * s - zs, (float)q1.y * s - zs);
    o.w = pack2((float)q1.z * s - zs, (float)q1.w * s - zs);
    *(uint4*)(W + (size_t)n * K + k) = o;
}

// ---------------- Pass 2: bf16 GEMM, m97 structure ----------------
__global__ __launch_bounds__(256, 2)
void gemm_bt_kernel(const unsigned short* __restrict__ Ab,
                    const unsigned short* __restrict__ Wb,
                    const float* __restrict__ bias, float* __restrict__ C,
                    int M, int N, int K)
{
    // Unpadded tiles: required by global_load_lds (wave base + lane*16 layout)
    __shared__ __align__(16) unsigned short As[BM * BK];
    __shared__ __align__(16) unsigned short Bs[BN * BK];

    const int tid = threadIdx.x;
    const int m0  = blockIdx.x * BM;   // M fastest: consecutive blocks share B panel
    const int n0  = blockIdx.y * BN;

    const int lane = tid & 63;
    const int wave = tid >> 6;
    const int wm   = (wave >> 1) * 64;
    const int wn   = (wave & 1) * 64;
    const int fr   = lane & 15;
    const int quad = lane >> 4;

    f32x4 acc[4][4];
    #pragma unroll
    for (int i = 0; i < 4; ++i)
        #pragma unroll
        for (int j = 0; j < 4; ++j)
            acc[i][j] = (f32x4){0.f, 0.f, 0.f, 0.f};

    const int ktiles = K / BK;
    for (int kt = 0; kt < ktiles; ++kt) {
        const int k0 = kt * BK;
        // stage both tiles: 4 chunks of 16B per thread per tile
        #pragma unroll
        for (int i = 0; i < 4; ++i) {
            const int c    = i * 256 + tid;     // chunk id 0..1023
            const int row  = c >> 3;            // tile row 0..127
            const int cole = (c & 7) * 8;       // elem col 0..56
            gl_lds16(Ab + (size_t)(m0 + row) * K + k0 + cole, (char*)As + c * 16);
            gl_lds16(Wb + (size_t)(n0 + row) * K + k0 + cole, (char*)Bs + c * 16);
        }
        __syncthreads();

        #pragma unroll
        for (int ks = 0; ks < 2; ++ks) {
            bf16x8 af[4], bfg[4];
            #pragma unroll
            for (int i = 0; i < 4; ++i)
                af[i] = *(const bf16x8*)&As[(wm + i * 16 + fr) * BK + ks * 32 + quad * 8];
            #pragma unroll
            for (int j = 0; j < 4; ++j)
                bfg[j] = *(const bf16x8*)&Bs[(wn + j * 16 + fr) * BK + ks * 32 + quad * 8];
            #pragma unroll
            for (int i = 0; i < 4; ++i)
                #pragma unroll
                for (int j = 0; j < 4; ++j)
                    acc[i][j] = __builtin_amdgcn_mfma_f32_16x16x32_bf16(af[i], bfg[j], acc[i][j], 0, 0, 0);
        }
        __syncthreads();
    }

    // D layout: col = lane&15 (n), row = quad*4 + reg (m)
    #pragma unroll
    for (int j = 0; j < 4; ++j) {
        const int n = n0 + wn + j * 16 + fr;
        const float bv = bias[n];
        #pragma unroll
        for (int i = 0; i < 4; ++i) {
            const int mb = m0 + wm + i * 16 + quad * 4;
            #pragma unroll
            for (int r = 0; r < 4; ++r)
                C[(size_t)(mb + r) * N + n] = acc[i][j][r] + bv;
        }
    }
}

// ---------------- Fallback: round-1 fused kernel ----------------
__global__ __launch_bounds__(256, 2)
void q4gemm_fused(const float* __restrict__ A, const int* __restrict__ Q,
                  const float* __restrict__ S, const int* __restrict__ Zp,
                  const float* __restrict__ bias, float* __restrict__ C,
                  int M, int N, int K, int nb)
{
    __shared__ __align__(16) unsigned short As[BM * LDSN];
    __shared__ __align__(16) unsigned short Bs[BN * LDSN];

    const int tid = threadIdx.x;
    const int m0  = blockIdx.x * BM;
    const int n0  = blockIdx.y * BN;
    const int srow = tid >> 4;
    const int scol = (tid & 15) << 2;
    const int lane = tid & 63;
    const int wave = tid >> 6;
    const int wm   = (wave >> 1) * 64;
    const int wn   = (wave & 1) * 64;
    const int fr   = lane & 15;
    const int quad = lane >> 4;

    f32x4 acc[4][4];
    #pragma unroll
    for (int i = 0; i < 4; ++i)
        #pragma unroll
        for (int j = 0; j < 4; ++j)
            acc[i][j] = (f32x4){0.f, 0.f, 0.f, 0.f};

    const int ktiles = K / BK;
    for (int kt = 0; kt < ktiles; ++kt) {
        const int k0 = kt * BK;
        #pragma unroll
        for (int i = 0; i < 8; ++i) {
            const int r = i * 16 + srow;
            const float4 v = *(const float4*)(A + (size_t)(m0 + r) * K + k0 + scol);
            uint2 p; p.x = pack2(v.x, v.y); p.y = pack2(v.z, v.w);
            *(uint2*)&As[r * LDSN + scol] = p;
        }
        #pragma unroll
        for (int i = 0; i < 8; ++i) {
            const int r = i * 16 + srow;
            const int n = n0 + r;
            const int4 q = *(const int4*)(Q + (size_t)n * K + k0 + scol);
            const float s  = S[(size_t)n * nb + kt];
            const float zs = (float)Zp[(size_t)n * nb + kt] * s;
            uint2 p;
            p.x = pack2((float)q.x * s - zs, (float)q.y * s - zs);
            p.y = pack2((float)q.z * s - zs, (float)q.w * s - zs);
            *(uint2*)&Bs[r * LDSN + scol] = p;
        }
        __syncthreads();
        #pragma unroll
        for (int ks = 0; ks < 2; ++ks) {
            bf16x8 af[4], bfg[4];
            #pragma unroll
            for (int i = 0; i < 4; ++i)
                af[i] = *(const bf16x8*)&As[(wm + i * 16 + fr) * LDSN + ks * 32 + quad * 8];
            #pragma unroll
            for (int j = 0; j < 4; ++j)
                bfg[j] = *(const bf16x8*)&Bs[(wn + j * 16 + fr) * LDSN + ks * 32 + quad * 8];
            #pragma unroll
            for (int i = 0; i < 4; ++i)
                #pragma unroll
                for (int j = 0; j < 4; ++j)
                    acc[i][j] = __builtin_amdgcn_mfma_f32_16x16x32_bf16(af[i], bfg[j], acc[i][j], 0, 0, 0);
        }
        __syncthreads();
    }
    #pragma unroll
    for (int j = 0; j < 4; ++j) {
        const int n = n0 + wn + j * 16 + fr;
        const float bv = bias[n];
        #pragma unroll
        for (int i = 0; i < 4; ++i) {
            const int mb = m0 + wm + i * 16 + quad * 4;
            #pragma unroll
            for (int r = 0; r < 4; ++r)
                C[(size_t)(mb + r) * N + n] = acc[i][j][r] + bv;
        }
    }
}

extern "C" void kernel_launch(void* const* d_in, const int* in_sizes, int n_in,
                              void* d_out, int out_size, void* d_ws, size_t ws_size,
                              hipStream_t stream) {
    const float* A    = (const float*)d_in[0];
    const int*   Q    = (const int*)d_in[1];
    const float* S    = (const float*)d_in[2];
    const int*   Zp   = (const int*)d_in[3];
    const float* bias = (const float*)d_in[4];
    float* C = (float*)d_out;

    const int N  = in_sizes[4];
    const int K  = in_sizes[1] / N;
    const int M  = in_sizes[0] / K;
    const int nb = in_sizes[2] / N;

    const size_t needA = (size_t)M * K * 2;
    const size_t needW = (size_t)N * K * 2;

    if (ws_size >= needA + needW) {
        unsigned short* Ab = (unsigned short*)d_ws;
        unsigned short* Wb = (unsigned short*)((char*)d_ws + needA);

        long total4 = (long)M * K / 4;
        a2bf_kernel<<<(unsigned)((total4 + 255) / 256), 256, 0, stream>>>(A, Ab, total4);

        long total8 = (long)N * K / 8;
        dequant_kernel<<<(unsigned)((total8 + 255) / 256), 256, 0, stream>>>(Q, S, Zp, Wb, N, K, nb);

        dim3 grid(M / BM, N / BN);
        gemm_bt_kernel<<<grid, dim3(256), 0, stream>>>(Ab, Wb, bias, C, M, N, K);
    } else {
        dim3 grid(M / BM, N / BN);
        q4gemm_fused<<<grid, dim3(256), 0, stream>>>(A, Q, S, Zp, bias, C, M, N, K, nb);
    }
}

// Round 3
// 668.022 us; speedup vs baseline: 1.7092x; 1.1648x over previous
//
#include <hip/hip_runtime.h>

// BlkQ4Linear: out[m,n] = sum_k in[m,k]*(q[n,k]-zp[n,k/64])*s[n,k/64] + bias[n]
// M=4096 K=4096 N=11008.
// Round 3: XOR-swizzled LDS layout in the GEMM to kill ds_read_b128 bank
// conflicts (R2 showed 1.35e8 conflict cycles; quad-uniform chunk position
// meant 16 lanes per 4-bank group). Swizzle is applied on the *global source
// column* during global_load_lds staging (LDS dst stays lane-contiguous, as
// the HW requires), and inverted in the fragment-read addressing.
// Pre-pass: dequant uses 2D grid (no 64-bit div).

#define BM 128
#define BN 128
#define BK 64
#define LDSN 72  // fused-fallback LDS pad

typedef __attribute__((ext_vector_type(8))) short bf16x8;
typedef __attribute__((ext_vector_type(4))) float f32x4;

__device__ __forceinline__ unsigned short f2bf(float f) {
    union { float f; unsigned int u; } v; v.f = f;
    unsigned int u = v.u;
    u += 0x7FFFu + ((u >> 16) & 1u);   // RNE
    return (unsigned short)(u >> 16);
}
__device__ __forceinline__ unsigned int pack2(float a, float b) {
    return (unsigned int)f2bf(a) | ((unsigned int)f2bf(b) << 16);
}

__device__ __forceinline__ void gl_lds16(const void* gp, void* lp) {
    __builtin_amdgcn_global_load_lds(
        (const __attribute__((address_space(1))) unsigned int*)gp,
        (__attribute__((address_space(3))) unsigned int*)lp,
        16, 0, 0);
}

// ---------------- Pass 1a: A fp32 -> bf16 ----------------
__global__ __launch_bounds__(256)
void a2bf_kernel(const float* __restrict__ A, unsigned short* __restrict__ Ab,
                 long total4)
{
    long t = (long)blockIdx.x * blockDim.x + threadIdx.x;
    if (t >= total4) return;
    float4 v = ((const float4*)A)[t];
    uint2 p; p.x = pack2(v.x, v.y); p.y = pack2(v.z, v.w);
    ((uint2*)Ab)[t] = p;
}

// ---------------- Pass 1b: Q int32 codes -> bf16 W ----------------
// 2D grid: blockIdx.y = n row, blockIdx.x covers K/8 chunks. No 64-bit div.
__global__ __launch_bounds__(256)
void dequant_kernel(const int* __restrict__ Q, const float* __restrict__ S,
                    const int* __restrict__ Zp, unsigned short* __restrict__ W,
                    int K, int nb)
{
    const int n = blockIdx.y;
    const int k = (blockIdx.x * 256 + threadIdx.x) * 8;
    if (k >= K) return;
    const int kb = k >> 6;
    const float s  = S[(size_t)n * nb + kb];
    const float zs = (float)Zp[(size_t)n * nb + kb] * s;
    const int4* qp = (const int4*)(Q + (size_t)n * K + k);
    int4 q0 = qp[0], q1 = qp[1];
    uint4 o;
    o.x = pack2((float)q0.x * s - zs, (float)q0.y * s - zs);
    o.y = pack2((float)q0.z * s - zs, (float)q0.w * s - zs);
    o.z = pack2((float)q1.x * s - zs, (float)q1.y * s - zs);
    o.w = pack2((float)q1.z * s - zs, (float)q1.w * s - zs);
    *(uint4*)(W + (size_t)n * K + k) = o;
}

// ---------------- Pass 2: bf16 GEMM, m97 structure + XOR swizzle ----------------
__global__ __launch_bounds__(256, 2)
void gemm_bt_kernel(const unsigned short* __restrict__ Ab,
                    const unsigned short* __restrict__ Wb,
                    const float* __restrict__ bias, float* __restrict__ C,
                    int M, int N, int K)
{
    __shared__ __align__(16) unsigned short As[BM * BK];
    __shared__ __align__(16) unsigned short Bs[BN * BK];

    const int tid = threadIdx.x;
    const int m0  = blockIdx.x * BM;   // M fastest: consecutive blocks share B panel
    const int n0  = blockIdx.y * BN;

    const int lane = tid & 63;
    const int wave = tid >> 6;
    const int wm   = (wave >> 1) * 64;
    const int wn   = (wave & 1) * 64;
    const int fr   = lane & 15;
    const int quad = lane >> 4;
    const int sw   = fr & 7;           // per-lane row-swizzle key (row&7 == fr&7)

    f32x4 acc[4][4];
    #pragma unroll
    for (int i = 0; i < 4; ++i)
        #pragma unroll
        for (int j = 0; j < 4; ++j)
            acc[i][j] = (f32x4){0.f, 0.f, 0.f, 0.f};

    const int ktiles = K / BK;
    for (int kt = 0; kt < ktiles; ++kt) {
        const int k0 = kt * BK;
        // Stage both tiles: chunk c -> LDS offset c*16 (lane-contiguous, HW reqt);
        // global source column-chunk is XOR-permuted within the row so that
        // physical chunk p holds logical chunk p^(row&7).
        #pragma unroll
        for (int i = 0; i < 4; ++i) {
            const int c    = i * 256 + tid;            // chunk id 0..1023
            const int row  = c >> 3;                   // tile row 0..127
            const int g    = (c & 7) ^ (row & 7);      // swizzled source chunk
            const int cole = g * 8;                    // elem col
            gl_lds16(Ab + (size_t)(m0 + row) * K + k0 + cole, (char*)As + c * 16);
            gl_lds16(Wb + (size_t)(n0 + row) * K + k0 + cole, (char*)Bs + c * 16);
        }
        __syncthreads();

        #pragma unroll
        for (int ks = 0; ks < 2; ++ks) {
            bf16x8 af[4], bfg[4];
            #pragma unroll
            for (int i = 0; i < 4; ++i) {
                const int row = wm + i * 16 + fr;
                const int p   = (ks * 4 + quad) ^ sw;  // physical chunk
                af[i] = *(const bf16x8*)&As[row * BK + p * 8];
            }
            #pragma unroll
            for (int j = 0; j < 4; ++j) {
                const int row = wn + j * 16 + fr;
                const int p   = (ks * 4 + quad) ^ sw;
                bfg[j] = *(const bf16x8*)&Bs[row * BK + p * 8];
            }
            #pragma unroll
            for (int i = 0; i < 4; ++i)
                #pragma unroll
                for (int j = 0; j < 4; ++j)
                    acc[i][j] = __builtin_amdgcn_mfma_f32_16x16x32_bf16(af[i], bfg[j], acc[i][j], 0, 0, 0);
        }
        __syncthreads();
    }

    // D layout: col = lane&15 (n), row = quad*4 + reg (m)
    #pragma unroll
    for (int j = 0; j < 4; ++j) {
        const int n = n0 + wn + j * 16 + fr;
        const float bv = bias[n];
        #pragma unroll
        for (int i = 0; i < 4; ++i) {
            const int mb = m0 + wm + i * 16 + quad * 4;
            #pragma unroll
            for (int r = 0; r < 4; ++r)
                C[(size_t)(mb + r) * N + n] = acc[i][j][r] + bv;
        }
    }
}

// ---------------- Fallback: round-1 fused kernel ----------------
__global__ __launch_bounds__(256, 2)
void q4gemm_fused(const float* __restrict__ A, const int* __restrict__ Q,
                  const float* __restrict__ S, const int* __restrict__ Zp,
                  const float* __restrict__ bias, float* __restrict__ C,
                  int M, int N, int K, int nb)
{
    __shared__ __align__(16) unsigned short As[BM * LDSN];
    __shared__ __align__(16) unsigned short Bs[BN * LDSN];

    const int tid = threadIdx.x;
    const int m0  = blockIdx.x * BM;
    const int n0  = blockIdx.y * BN;
    const int srow = tid >> 4;
    const int scol = (tid & 15) << 2;
    const int lane = tid & 63;
    const int wave = tid >> 6;
    const int wm   = (wave >> 1) * 64;
    const int wn   = (wave & 1) * 64;
    const int fr   = lane & 15;
    const int quad = lane >> 4;

    f32x4 acc[4][4];
    #pragma unroll
    for (int i = 0; i < 4; ++i)
        #pragma unroll
        for (int j = 0; j < 4; ++j)
            acc[i][j] = (f32x4){0.f, 0.f, 0.f, 0.f};

    const int ktiles = K / BK;
    for (int kt = 0; kt < ktiles; ++kt) {
        const int k0 = kt * BK;
        #pragma unroll
        for (int i = 0; i < 8; ++i) {
            const int r = i * 16 + srow;
            const float4 v = *(const float4*)(A + (size_t)(m0 + r) * K + k0 + scol);
            uint2 p; p.x = pack2(v.x, v.y); p.y = pack2(v.z, v.w);
            *(uint2*)&As[r * LDSN + scol] = p;
        }
        #pragma unroll
        for (int i = 0; i < 8; ++i) {
            const int r = i * 16 + srow;
            const int n = n0 + r;
            const int4 q = *(const int4*)(Q + (size_t)n * K + k0 + scol);
            const float s  = S[(size_t)n * nb + kt];
            const float zs = (float)Zp[(size_t)n * nb + kt] * s;
            uint2 p;
            p.x = pack2((float)q.x * s - zs, (float)q.y * s - zs);
            p.y = pack2((float)q.z * s - zs, (float)q.w * s - zs);
            *(uint2*)&Bs[r * LDSN + scol] = p;
        }
        __syncthreads();
        #pragma unroll
        for (int ks = 0; ks < 2; ++ks) {
            bf16x8 af[4], bfg[4];
            #pragma unroll
            for (int i = 0; i < 4; ++i)
                af[i] = *(const bf16x8*)&As[(wm + i * 16 + fr) * LDSN + ks * 32 + quad * 8];
            #pragma unroll
            for (int j = 0; j < 4; ++j)
                bfg[j] = *(const bf16x8*)&Bs[(wn + j * 16 + fr) * LDSN + ks * 32 + quad * 8];
            #pragma unroll
            for (int i = 0; i < 4; ++i)
                #pragma unroll
                for (int j = 0; j < 4; ++j)
                    acc[i][j] = __builtin_amdgcn_mfma_f32_16x16x32_bf16(af[i], bfg[j], acc[i][j], 0, 0, 0);
        }
        __syncthreads();
    }
    #pragma unroll
    for (int j = 0; j < 4; ++j) {
        const int n = n0 + wn + j * 16 + fr;
        const float bv = bias[n];
        #pragma unroll
        for (int i = 0; i < 4; ++i) {
            const int mb = m0 + wm + i * 16 + quad * 4;
            #pragma unroll
            for (int r = 0; r < 4; ++r)
                C[(size_t)(mb + r) * N + n] = acc[i][j][r] + bv;
        }
    }
}

extern "C" void kernel_launch(void* const* d_in, const int* in_sizes, int n_in,
                              void* d_out, int out_size, void* d_ws, size_t ws_size,
                              hipStream_t stream) {
    const float* A    = (const float*)d_in[0];
    const int*   Q    = (const int*)d_in[1];
    const float* S    = (const float*)d_in[2];
    const int*   Zp   = (const int*)d_in[3];
    const float* bias = (const float*)d_in[4];
    float* C = (float*)d_out;

    const int N  = in_sizes[4];
    const int K  = in_sizes[1] / N;
    const int M  = in_sizes[0] / K;
    const int nb = in_sizes[2] / N;

    const size_t needA = (size_t)M * K * 2;
    const size_t needW = (size_t)N * K * 2;

    if (ws_size >= needA + needW) {
        unsigned short* Ab = (unsigned short*)d_ws;
        unsigned short* Wb = (unsigned short*)((char*)d_ws + needA);

        long total4 = (long)M * K / 4;
        a2bf_kernel<<<(unsigned)((total4 + 255) / 256), 256, 0, stream>>>(A, Ab, total4);

        dim3 dq_grid((K / 8 + 255) / 256, N);
        dequant_kernel<<<dq_grid, 256, 0, stream>>>(Q, S, Zp, Wb, K, nb);

        dim3 grid(M / BM, N / BN);
        gemm_bt_kernel<<<grid, dim3(256), 0, stream>>>(Ab, Wb, bias, C, M, N, K);
    } else {
        dim3 grid(M / BM, N / BN);
        q4gemm_fused<<<grid, dim3(256), 0, stream>>>(A, Q, S, Zp, bias, C, M, N, K, nb);
    }
}